// Round 1
// baseline (2253.780 us; speedup 1.0000x reference)
//
#include <hip/hip_runtime.h>

static constexpr int FDIM = 128;
static constexpr int ND1  = 131072;
static constexpr int ND2  = 8192;
static constexpr int GEMM_R = 8;

// One wave (64 lanes) per edge: gather 512B source row, atomic-scatter into agg[dst].
__global__ void scatter_kernel(const float* __restrict__ src,
                               const int* __restrict__ esrc,
                               const int* __restrict__ edst,
                               float* __restrict__ agg,
                               float* __restrict__ deg,
                               int E) {
  const int lane = threadIdx.x & 63;
  const int wid  = (int)((blockIdx.x * (unsigned)blockDim.x + threadIdx.x) >> 6);
  if (wid >= E) return;
  const int s = esrc[wid];
  const int d = edst[wid];
  const float2 v = *reinterpret_cast<const float2*>(src + (size_t)s * FDIM + lane * 2);
  float* a = agg + (size_t)d * FDIM + lane * 2;
  atomicAdd(a + 0, v.x);
  atomicAdd(a + 1, v.y);
  if (lane == 0) atomicAdd(deg + d, 1.0f);
}

// Out[row] = act( Aself[row] @ Wself + (Aagg[row]/max(Deg,1)) @ Wneigh + bias )
// thread = (f = col, m = which matrix). W column lives in 128 VGPRs (full unroll).
// A-row loads are wave-uniform -> SMEM (s_load) stream, VALU does pure FMA.
template<bool RELU>
__global__ __launch_bounds__(256)
void sage_gemm(const float* __restrict__ Aself,
               const float* __restrict__ Aagg,
               const float* __restrict__ Deg,
               const float* __restrict__ Wself,
               const float* __restrict__ Wneigh,
               const float* __restrict__ bias,
               float* __restrict__ Out,
               int rows_per_block)
{
  const int f  = threadIdx.x & 127;
  const int m  = threadIdx.x >> 7;                  // waves 0,1 -> 0 ; waves 2,3 -> 1
  const int mu = __builtin_amdgcn_readfirstlane(m); // force wave-uniform for SMEM path

  const float* __restrict__ W = mu ? Wneigh : Wself;
  const float* __restrict__ A = mu ? Aagg   : Aself;

  float w[FDIM];
  #pragma unroll
  for (int k = 0; k < FDIM; ++k) w[k] = W[(size_t)k * FDIM + f];
  const float bf = bias[f];

  __shared__ float red[GEMM_R][FDIM];

  const int row0 = blockIdx.x * rows_per_block;
  for (int r0 = row0; r0 < row0 + rows_per_block; r0 += GEMM_R) {
    float acc[GEMM_R];
    #pragma unroll
    for (int r = 0; r < GEMM_R; ++r) acc[r] = 0.0f;

    #pragma unroll
    for (int k = 0; k < FDIM; ++k) {
      const float wk = w[k];
      #pragma unroll
      for (int r = 0; r < GEMM_R; ++r)
        acc[r] = fmaf(A[(size_t)(r0 + r) * FDIM + k], wk, acc[r]);
    }

    if (mu) {
      #pragma unroll
      for (int r = 0; r < GEMM_R; ++r) {
        const float minv = 1.0f / fmaxf(Deg[r0 + r], 1.0f);
        red[r][f] = acc[r] * minv;
      }
    }
    __syncthreads();
    if (!mu) {
      #pragma unroll
      for (int r = 0; r < GEMM_R; ++r) {
        float y = acc[r] + red[r][f] + bf;
        if (RELU) y = fmaxf(y, 0.0f);
        Out[(size_t)(r0 + r) * FDIM + f] = y;
      }
    }
    __syncthreads();
  }
}

extern "C" void kernel_launch(void* const* d_in, const int* in_sizes, int n_in,
                              void* d_out, int out_size, void* d_ws, size_t ws_size,
                              hipStream_t stream) {
  const float* x   = (const float*)d_in[0];
  const int*   e1s = (const int*)d_in[1];
  const int*   e1d = (const int*)d_in[2];
  const int*   e2s = (const int*)d_in[3];
  const int*   e2d = (const int*)d_in[4];
  const float* Ws1 = (const float*)d_in[7];
  const float* Wn1 = (const float*)d_in[8];
  const float* b1  = (const float*)d_in[9];
  const float* Ws2 = (const float*)d_in[10];
  const float* Wn2 = (const float*)d_in[11];
  const float* b2  = (const float*)d_in[12];
  const int E1 = in_sizes[1];
  const int E2 = in_sizes[3];

  char* ws = (char*)d_ws;
  const size_t AGG1_B = (size_t)ND1 * FDIM * sizeof(float);  // 64 MiB (reused as h)
  const size_t AGG2_B = (size_t)ND2 * FDIM * sizeof(float);  // 4 MiB
  const size_t DEG1_B = (size_t)ND1 * sizeof(float);
  const size_t DEG2_B = (size_t)ND2 * sizeof(float);
  float* agg1 = (float*)(ws);
  float* agg2 = (float*)(ws + AGG1_B);
  float* deg1 = (float*)(ws + AGG1_B + AGG2_B);
  float* deg2 = (float*)(ws + AGG1_B + AGG2_B + DEG1_B);

  // zero accumulators (atomics add into them); h overwrites agg1 in-place later
  hipMemsetAsync(d_ws, 0, AGG1_B + AGG2_B + DEG1_B + DEG2_B, stream);

  // Layer 1: scatter-mean over x, then GEMM+ReLU -> h (in-place over agg1)
  scatter_kernel<<<(E1 + 3) / 4, 256, 0, stream>>>(x, e1s, e1d, agg1, deg1, E1);
  sage_gemm<true ><<<1024, 256, 0, stream>>>(x, agg1, deg1, Ws1, Wn1, b1, agg1, ND1 / 1024);

  // Layer 2: scatter-mean over h, then GEMM -> out
  scatter_kernel<<<(E2 + 3) / 4, 256, 0, stream>>>(agg1, e2s, e2d, agg2, deg2, E2);
  sage_gemm<false><<<1024, 256, 0, stream>>>(agg1, agg2, deg2, Ws2, Wn2, b2, (float*)d_out, ND2 / 1024);
}

// Round 2
// 1041.038 us; speedup vs baseline: 2.1649x; 2.1649x over previous
//
#include <hip/hip_runtime.h>

static constexpr int FDIM = 128;
static constexpr int ND1  = 131072;
static constexpr int ND2  = 8192;
static constexpr int GEMM_R = 8;

// --- CSR build ---------------------------------------------------------------
__global__ void hist_kernel(const int* __restrict__ edst, int* __restrict__ cnt, int E) {
  int e = blockIdx.x * 256 + threadIdx.x;
  if (e < E) atomicAdd(&cnt[edst[e]], 1);
}

// In-place exclusive scan of c[0..n), total written to c[n]. Single block, 1024 thr.
__global__ __launch_bounds__(1024) void scan_kernel(int* __restrict__ c, int n) {
  const int tid = threadIdx.x;
  const int chunk = n >> 10;                 // n is 131072 or 8192
  const int base = tid * chunk;
  int s = 0;
  for (int j = 0; j < chunk; ++j) s += c[base + j];
  __shared__ int ps[1024];
  ps[tid] = s;
  __syncthreads();
  for (int off = 1; off < 1024; off <<= 1) {  // Hillis-Steele inclusive scan
    int v = (tid >= off) ? ps[tid - off] : 0;
    __syncthreads();
    ps[tid] += v;
    __syncthreads();
  }
  int run = (tid == 0) ? 0 : ps[tid - 1];
  for (int j = 0; j < chunk; ++j) { int v = c[base + j]; c[base + j] = run; run += v; }
  if (tid == 1023) c[n] = run;
}

__global__ void fill_kernel(const int* __restrict__ esrc, const int* __restrict__ edst,
                            const int* __restrict__ rs, int* __restrict__ cur,
                            int* __restrict__ csr, int E) {
  int e = blockIdx.x * 256 + threadIdx.x;
  if (e >= E) return;
  int d = edst[e];
  int p = atomicAdd(&cur[d], 1);
  csr[rs[d] + p] = esrc[e];
}

// --- Gather-mean: one wave per dst row; lane covers float2 of the 128-f row --
__global__ void gather_mean_kernel(const float* __restrict__ src,
                                   const int* __restrict__ csr,
                                   const int* __restrict__ rs,
                                   float* __restrict__ out, int nrows) {
  const int lane = threadIdx.x & 63;
  int row = (int)((blockIdx.x * (unsigned)blockDim.x + threadIdx.x) >> 6);
  row = __builtin_amdgcn_readfirstlane(row);   // wave-uniform -> scalar loads for csr/rs
  if (row >= nrows) return;
  const int start = rs[row], end = rs[row + 1];
  float ax = 0.f, ay = 0.f;
  int i = start;
  for (; i + 4 <= end; i += 4) {               // 4 independent row-loads in flight
    int s0 = csr[i + 0], s1 = csr[i + 1], s2 = csr[i + 2], s3 = csr[i + 3];
    const float2 v0 = *(const float2*)(src + (size_t)s0 * FDIM + lane * 2);
    const float2 v1 = *(const float2*)(src + (size_t)s1 * FDIM + lane * 2);
    const float2 v2 = *(const float2*)(src + (size_t)s2 * FDIM + lane * 2);
    const float2 v3 = *(const float2*)(src + (size_t)s3 * FDIM + lane * 2);
    ax += v0.x + v1.x + v2.x + v3.x;
    ay += v0.y + v1.y + v2.y + v3.y;
  }
  for (; i < end; ++i) {
    int s0 = csr[i];
    const float2 v0 = *(const float2*)(src + (size_t)s0 * FDIM + lane * 2);
    ax += v0.x; ay += v0.y;
  }
  const int deg = end - start;
  const float inv = 1.0f / (float)(deg > 1 ? deg : 1);
  float2 o; o.x = ax * inv; o.y = ay * inv;
  *(float2*)(out + (size_t)row * FDIM + lane * 2) = o;
}

// --- Fused dual GEMM: Out = act(Aself@Wself + Amean@Wneigh + b) --------------
// thread = (f = col, m = which matrix). W column in 128 VGPRs; A-row loads uniform.
template<bool RELU>
__global__ __launch_bounds__(256)
void sage_gemm(const float* __restrict__ Aself,
               const float* __restrict__ Amean,
               const float* __restrict__ Wself,
               const float* __restrict__ Wneigh,
               const float* __restrict__ bias,
               float* __restrict__ Out,
               int rows_per_block)
{
  const int f  = threadIdx.x & 127;
  const int m  = threadIdx.x >> 7;
  const int mu = __builtin_amdgcn_readfirstlane(m);

  const float* __restrict__ W = mu ? Wneigh : Wself;
  const float* __restrict__ A = mu ? Amean  : Aself;

  float w[FDIM];
  #pragma unroll
  for (int k = 0; k < FDIM; ++k) w[k] = W[(size_t)k * FDIM + f];
  const float bf = bias[f];

  __shared__ float red[GEMM_R][FDIM];

  const int row0 = blockIdx.x * rows_per_block;
  for (int r0 = row0; r0 < row0 + rows_per_block; r0 += GEMM_R) {
    float acc[GEMM_R];
    #pragma unroll
    for (int r = 0; r < GEMM_R; ++r) acc[r] = 0.0f;

    #pragma unroll
    for (int k = 0; k < FDIM; ++k) {
      const float wk = w[k];
      #pragma unroll
      for (int r = 0; r < GEMM_R; ++r)
        acc[r] = fmaf(A[(size_t)(r0 + r) * FDIM + k], wk, acc[r]);
    }

    if (mu) {
      #pragma unroll
      for (int r = 0; r < GEMM_R; ++r) red[r][f] = acc[r];
    }
    __syncthreads();
    if (!mu) {
      #pragma unroll
      for (int r = 0; r < GEMM_R; ++r) {
        float y = acc[r] + red[r][f] + bf;
        if (RELU) y = fmaxf(y, 0.0f);
        Out[(size_t)(r0 + r) * FDIM + f] = y;
      }
    }
    __syncthreads();
  }
}

extern "C" void kernel_launch(void* const* d_in, const int* in_sizes, int n_in,
                              void* d_out, int out_size, void* d_ws, size_t ws_size,
                              hipStream_t stream) {
  const float* x   = (const float*)d_in[0];
  const int*   e1s = (const int*)d_in[1];
  const int*   e1d = (const int*)d_in[2];
  const int*   e2s = (const int*)d_in[3];
  const int*   e2d = (const int*)d_in[4];
  const float* Ws1 = (const float*)d_in[7];
  const float* Wn1 = (const float*)d_in[8];
  const float* b1  = (const float*)d_in[9];
  const float* Ws2 = (const float*)d_in[10];
  const float* Wn2 = (const float*)d_in[11];
  const float* b2  = (const float*)d_in[12];
  const int E1 = in_sizes[1];
  const int E2 = in_sizes[3];

  // workspace layout
  char* p = (char*)d_ws;
  float* agg1 = (float*)p;            p += (size_t)ND1 * FDIM * sizeof(float); // 64 MiB, later h
  char*  aux  = p;                                                             // agg2 region (4 MiB)
  float* agg2 = (float*)p;            p += (size_t)ND2 * FDIM * sizeof(float);
  int*   csr1 = (int*)p;              p += (size_t)E1 * sizeof(int);
  int*   csr2 = (int*)p;              p += (size_t)E2 * sizeof(int);
  int*   rs1  = (int*)p;              p += (size_t)(ND1 + 1) * sizeof(int);
  int*   rs2  = (int*)p;              p += (size_t)(ND2 + 1) * sizeof(int);
  // cursors overlaid on agg2 (agg2 only written by gather2, after fills complete)
  int* cur1 = (int*)aux;
  int* cur2 = (int*)(aux + (size_t)ND1 * sizeof(int));

  hipMemsetAsync(rs1, 0, (size_t)(ND1 + 1 + ND2 + 1) * sizeof(int), stream);
  hipMemsetAsync(cur1, 0, (size_t)(ND1 + ND2) * sizeof(int), stream);

  // CSR build (both graphs)
  hist_kernel<<<(E1 + 255) / 256, 256, 0, stream>>>(e1d, rs1, E1);
  hist_kernel<<<(E2 + 255) / 256, 256, 0, stream>>>(e2d, rs2, E2);
  scan_kernel<<<1, 1024, 0, stream>>>(rs1, ND1);
  scan_kernel<<<1, 1024, 0, stream>>>(rs2, ND2);
  fill_kernel<<<(E1 + 255) / 256, 256, 0, stream>>>(e1s, e1d, rs1, cur1, csr1, E1);
  fill_kernel<<<(E2 + 255) / 256, 256, 0, stream>>>(e2s, e2d, rs2, cur2, csr2, E2);

  // Layer 1: gather-mean over x -> agg1, then GEMM+ReLU -> h (in-place over agg1)
  gather_mean_kernel<<<ND1 / 4, 256, 0, stream>>>(x, csr1, rs1, agg1, ND1);
  sage_gemm<true ><<<1024, 256, 0, stream>>>(x, agg1, Ws1, Wn1, b1, agg1, ND1 / 1024);

  // Layer 2: gather-mean over h -> agg2, then GEMM -> out
  gather_mean_kernel<<<ND2 / 4, 256, 0, stream>>>(agg1, csr2, rs2, agg2, ND2);
  sage_gemm<false><<<1024, 256, 0, stream>>>(agg1, agg2, Ws2, Wn2, b2, (float*)d_out, ND2 / 1024);
}

// Round 3
// 731.689 us; speedup vs baseline: 3.0802x; 1.4228x over previous
//
#include <hip/hip_runtime.h>

static constexpr int FDIM = 128;
static constexpr int ND1  = 131072;
static constexpr int ND2  = 8192;

// --- CSR build ---------------------------------------------------------------
__global__ void hist_kernel(const int* __restrict__ edst, int* __restrict__ cnt, int E) {
  int e = blockIdx.x * 256 + threadIdx.x;
  if (e < E) atomicAdd(&cnt[edst[e]], 1);
}

// In-place exclusive scan of c[0..n), total -> c[n]. Single block, 1024 thr.
__global__ __launch_bounds__(1024) void scan_kernel(int* __restrict__ c, int n) {
  const int tid = threadIdx.x;
  const int chunk = n >> 10;
  const int base = tid * chunk;
  int s = 0;
  for (int j = 0; j < chunk; ++j) s += c[base + j];
  __shared__ int ps[1024];
  ps[tid] = s;
  __syncthreads();
  for (int off = 1; off < 1024; off <<= 1) {
    int v = (tid >= off) ? ps[tid - off] : 0;
    __syncthreads();
    ps[tid] += v;
    __syncthreads();
  }
  int run = (tid == 0) ? 0 : ps[tid - 1];
  for (int j = 0; j < chunk; ++j) { int v = c[base + j]; c[base + j] = run; run += v; }
  if (tid == 1023) c[n] = run;
}

__global__ void fill_kernel(const int* __restrict__ esrc, const int* __restrict__ edst,
                            const int* __restrict__ rs, int* __restrict__ cur,
                            int* __restrict__ csr, int E) {
  int e = blockIdx.x * 256 + threadIdx.x;
  if (e >= E) return;
  int d = edst[e];
  int p = atomicAdd(&cur[d], 1);
  csr[rs[d] + p] = esrc[e];
}

// --- Gather-mean v2: wave per dst row; two edges per load instr (float4/lane),
// 8-edge unroll (4 x 1KB loads in flight), cross-half shfl reduce at the end.
__global__ __launch_bounds__(256)
void gather_mean_kernel(const float* __restrict__ src,
                        const int* __restrict__ csr,
                        const int* __restrict__ rs,
                        float* __restrict__ out, int nrows) {
  const int lane = threadIdx.x & 63;
  const int half = lane >> 5;          // which edge of a pair
  const int sub  = lane & 31;          // covers features sub*4 .. sub*4+3
  int row = (int)((blockIdx.x * (unsigned)blockDim.x + threadIdx.x) >> 6);
  row = __builtin_amdgcn_readfirstlane(row);   // wave-uniform
  if (row >= nrows) return;
  const int start = rs[row], end = rs[row + 1];
  float ax = 0.f, ay = 0.f, az = 0.f, aw = 0.f;
  int i = start;
  for (; i + 8 <= end; i += 8) {
    int s0 = csr[i + 0 + half];
    int s1 = csr[i + 2 + half];
    int s2 = csr[i + 4 + half];
    int s3 = csr[i + 6 + half];
    float4 v0 = *(const float4*)(src + (size_t)s0 * FDIM + sub * 4);
    float4 v1 = *(const float4*)(src + (size_t)s1 * FDIM + sub * 4);
    float4 v2 = *(const float4*)(src + (size_t)s2 * FDIM + sub * 4);
    float4 v3 = *(const float4*)(src + (size_t)s3 * FDIM + sub * 4);
    ax += v0.x + v1.x + v2.x + v3.x;
    ay += v0.y + v1.y + v2.y + v3.y;
    az += v0.z + v1.z + v2.z + v3.z;
    aw += v0.w + v1.w + v2.w + v3.w;
  }
  for (; i + 2 <= end; i += 2) {
    int s = csr[i + half];
    float4 v = *(const float4*)(src + (size_t)s * FDIM + sub * 4);
    ax += v.x; ay += v.y; az += v.z; aw += v.w;
  }
  if (i < end && half == 0) {          // odd remainder: half 0 only
    int s = csr[i];
    float4 v = *(const float4*)(src + (size_t)s * FDIM + sub * 4);
    ax += v.x; ay += v.y; az += v.z; aw += v.w;
  }
  ax += __shfl_xor(ax, 32);
  ay += __shfl_xor(ay, 32);
  az += __shfl_xor(az, 32);
  aw += __shfl_xor(aw, 32);
  if (half == 0) {
    const int deg = end - start;
    const float inv = 1.0f / (float)(deg > 1 ? deg : 1);
    float4 o; o.x = ax * inv; o.y = ay * inv; o.z = az * inv; o.w = aw * inv;
    *(float4*)(out + (size_t)row * FDIM + sub * 4) = o;
  }
}

// --- Fused GEMM: Out = act([Ax | Am] @ [Wx; Wm] + b), M-tile 128, K=256, N=128
// 256 thr, 8x8 micro-kernel, LDS-staged A (transposed) + W chunks of 32 k.
template<bool RELU>
__global__ __launch_bounds__(256)
void gemm_fused(const float* __restrict__ Ax, const float* __restrict__ Am,
                const float* __restrict__ Wx, const float* __restrict__ Wm,
                const float* __restrict__ bias, float* __restrict__ Out) {
  __shared__ float As[32][132];   // [k][row], padded: bank = (4k + r) % 32
  __shared__ float Ws[32][132];   // [k][col]
  const int tid  = threadIdx.x;
  const int tx   = tid & 15;      // col group: cols tx*8 .. +7
  const int ty   = tid >> 4;      // row group: rows ty*8 .. +7
  const int row0 = blockIdx.x * 128;

  float acc[8][8];
  #pragma unroll
  for (int i = 0; i < 8; ++i)
    #pragma unroll
    for (int j = 0; j < 8; ++j) acc[i][j] = 0.f;

  float bcol[8];
  #pragma unroll
  for (int j = 0; j < 8; ++j) bcol[j] = bias[tx * 8 + j];

  for (int c = 0; c < 8; ++c) {
    const int kc = (c & 3) * 32;
    const float* __restrict__ A = (c < 4) ? Ax : Am;
    const float* __restrict__ W = (c < 4) ? Wx : Wm;
    // stage A: rows row0..row0+127, cols kc..kc+31, transposed
    {
      const int r8 = tid >> 3;      // 0..31
      const int f4 = tid & 7;       // float4 within the 32 cols
      #pragma unroll
      for (int j = 0; j < 4; ++j) {
        const int r = r8 + j * 32;
        float4 v = *(const float4*)(A + (size_t)(row0 + r) * FDIM + kc + f4 * 4);
        As[f4 * 4 + 0][r] = v.x;
        As[f4 * 4 + 1][r] = v.y;
        As[f4 * 4 + 2][r] = v.z;
        As[f4 * 4 + 3][r] = v.w;
      }
      // stage W: rows kc..kc+31 (k), all 128 cols
      #pragma unroll
      for (int j = 0; j < 4; ++j) {
        const int idx = tid + j * 256;       // 0..1023
        const int k   = idx >> 5;
        const int f   = (idx & 31) * 4;
        float4 v = *(const float4*)(W + (size_t)(kc + k) * FDIM + f);
        *(float4*)&Ws[k][f] = v;
      }
    }
    __syncthreads();
    #pragma unroll
    for (int k = 0; k < 32; ++k) {
      float a[8], w[8];
      *(float4*)&a[0] = *(const float4*)&As[k][ty * 8];
      *(float4*)&a[4] = *(const float4*)&As[k][ty * 8 + 4];
      *(float4*)&w[0] = *(const float4*)&Ws[k][tx * 8];
      *(float4*)&w[4] = *(const float4*)&Ws[k][tx * 8 + 4];
      #pragma unroll
      for (int i = 0; i < 8; ++i)
        #pragma unroll
        for (int j = 0; j < 8; ++j)
          acc[i][j] = fmaf(a[i], w[j], acc[i][j]);
    }
    __syncthreads();
  }
  #pragma unroll
  for (int i = 0; i < 8; ++i) {
    const int r = row0 + ty * 8 + i;
    #pragma unroll
    for (int j = 0; j < 8; ++j) {
      float y = acc[i][j] + bcol[j];
      if (RELU) y = fmaxf(y, 0.f);
      acc[i][j] = y;
    }
    *(float4*)(Out + (size_t)r * FDIM + tx * 8)     = *(float4*)&acc[i][0];
    *(float4*)(Out + (size_t)r * FDIM + tx * 8 + 4) = *(float4*)&acc[i][4];
  }
}

extern "C" void kernel_launch(void* const* d_in, const int* in_sizes, int n_in,
                              void* d_out, int out_size, void* d_ws, size_t ws_size,
                              hipStream_t stream) {
  const float* x   = (const float*)d_in[0];
  const int*   e1s = (const int*)d_in[1];
  const int*   e1d = (const int*)d_in[2];
  const int*   e2s = (const int*)d_in[3];
  const int*   e2d = (const int*)d_in[4];
  const float* Ws1 = (const float*)d_in[7];
  const float* Wn1 = (const float*)d_in[8];
  const float* b1  = (const float*)d_in[9];
  const float* Ws2 = (const float*)d_in[10];
  const float* Wn2 = (const float*)d_in[11];
  const float* b2  = (const float*)d_in[12];
  const int E1 = in_sizes[1];
  const int E2 = in_sizes[3];

  char* p = (char*)d_ws;
  float* agg1 = (float*)p;            p += (size_t)ND1 * FDIM * sizeof(float); // 64 MiB, later h
  char*  aux  = p;
  float* agg2 = (float*)p;            p += (size_t)ND2 * FDIM * sizeof(float); // 4 MiB
  int*   csr1 = (int*)p;              p += (size_t)E1 * sizeof(int);
  int*   csr2 = (int*)p;              p += (size_t)E2 * sizeof(int);
  int*   rs1  = (int*)p;              p += (size_t)(ND1 + 1) * sizeof(int);
  int*   rs2  = (int*)p;              p += (size_t)(ND2 + 1) * sizeof(int);
  int* cur1 = (int*)aux;                       // overlaid on agg2 region
  int* cur2 = (int*)(aux + (size_t)ND1 * sizeof(int));

  hipMemsetAsync(rs1, 0, (size_t)(ND1 + 1 + ND2 + 1) * sizeof(int), stream);
  hipMemsetAsync(cur1, 0, (size_t)(ND1 + ND2) * sizeof(int), stream);

  hist_kernel<<<(E1 + 255) / 256, 256, 0, stream>>>(e1d, rs1, E1);
  hist_kernel<<<(E2 + 255) / 256, 256, 0, stream>>>(e2d, rs2, E2);
  scan_kernel<<<1, 1024, 0, stream>>>(rs1, ND1);
  scan_kernel<<<1, 1024, 0, stream>>>(rs2, ND2);
  fill_kernel<<<(E1 + 255) / 256, 256, 0, stream>>>(e1s, e1d, rs1, cur1, csr1, E1);
  fill_kernel<<<(E2 + 255) / 256, 256, 0, stream>>>(e2s, e2d, rs2, cur2, csr2, E2);

  // Layer 1
  gather_mean_kernel<<<ND1 / 4, 256, 0, stream>>>(x, csr1, rs1, agg1, ND1);
  gemm_fused<true ><<<ND1 / 128, 256, 0, stream>>>(x, agg1, Ws1, Wn1, b1, agg1);

  // Layer 2
  gather_mean_kernel<<<ND2 / 4, 256, 0, stream>>>(agg1, csr2, rs2, agg2, ND2);
  gemm_fused<false><<<ND2 / 128, 256, 0, stream>>>(agg1, agg2, Ws2, Wn2, b2, (float*)d_out);
}

// Round 4
// 499.567 us; speedup vs baseline: 4.5115x; 1.4646x over previous
//
#include <hip/hip_runtime.h>

static constexpr int FDIM = 128;
static constexpr int ND1  = 131072;
static constexpr int ND2  = 8192;
static constexpr int LDP  = 56;   // ushort stride for LDS tiles: 112B rows, 16B-aligned, ~2-way banks

using bf16x8 = __attribute__((ext_vector_type(8))) short;
using u16x8  = __attribute__((ext_vector_type(8))) unsigned short;
using f32x4  = __attribute__((ext_vector_type(4))) float;

static __device__ __forceinline__ unsigned short f2bf(float f) {
  unsigned u = __float_as_uint(f);
  u = (u + 0x7FFFu + ((u >> 16) & 1u)) >> 16;   // round-to-nearest-even
  return (unsigned short)u;
}
static __device__ __forceinline__ float bf2f(unsigned short s) {
  return __uint_as_float(((unsigned)s) << 16);
}

// ---------------- CSR build (merged, vectorized) -----------------------------
__global__ void hist_all(const int* __restrict__ e1d, const int* __restrict__ e2d,
                         int* __restrict__ rs1, int* __restrict__ rs2, int E1, int E2) {
  const int n1 = E1 >> 2, n2 = E2 >> 2;
  int t = blockIdx.x * 256 + threadIdx.x;
  if (t < n1) {
    int4 d = ((const int4*)e1d)[t];
    atomicAdd(&rs1[d.x], 1); atomicAdd(&rs1[d.y], 1);
    atomicAdd(&rs1[d.z], 1); atomicAdd(&rs1[d.w], 1);
  } else if (t < n1 + n2) {
    int4 d = ((const int4*)e2d)[t - n1];
    atomicAdd(&rs2[d.x], 1); atomicAdd(&rs2[d.y], 1);
    atomicAdd(&rs2[d.z], 1); atomicAdd(&rs2[d.w], 1);
  }
  if (blockIdx.x == 0) {               // generic tails
    int tt = threadIdx.x;
    if (tt < (E1 & 3)) atomicAdd(&rs1[e1d[E1 - 1 - tt]], 1);
    int t2 = tt - 8;
    if (t2 >= 0 && t2 < (E2 & 3)) atomicAdd(&rs2[e2d[E2 - 1 - t2]], 1);
  }
}

// block 0 scans c1[0..n1), block 1 scans c2[0..n2); total -> c[n]
__global__ __launch_bounds__(1024) void scan2_kernel(int* __restrict__ c1, int n1,
                                                     int* __restrict__ c2, int n2) {
  int* c = blockIdx.x ? c2 : c1;
  const int n = blockIdx.x ? n2 : n1;
  const int tid = threadIdx.x;
  const int chunk = n >> 10;
  const int base = tid * chunk;
  int s = 0;
  for (int j = 0; j < chunk; j += 4) {
    int4 v = *(const int4*)&c[base + j];
    s += v.x + v.y + v.z + v.w;
  }
  __shared__ int ps[1024];
  ps[tid] = s;
  __syncthreads();
  for (int off = 1; off < 1024; off <<= 1) {
    int v = (tid >= off) ? ps[tid - off] : 0;
    __syncthreads();
    ps[tid] += v;
    __syncthreads();
  }
  int run = (tid == 0) ? 0 : ps[tid - 1];
  for (int j = 0; j < chunk; j += 4) {
    int4 v = *(const int4*)&c[base + j];
    int4 o;
    o.x = run; run += v.x; o.y = run; run += v.y;
    o.z = run; run += v.z; o.w = run; run += v.w;
    *(int4*)&c[base + j] = o;
  }
  if (tid == 1023) c[n] = run;
}

__global__ void fill_all(const int* __restrict__ e1s, const int* __restrict__ e1d,
                         const int* __restrict__ e2s, const int* __restrict__ e2d,
                         const int* __restrict__ rs1, const int* __restrict__ rs2,
                         int* __restrict__ cur1, int* __restrict__ cur2,
                         int* __restrict__ csr1, int* __restrict__ csr2, int E1, int E2) {
  const int n1 = E1 >> 2, n2 = E2 >> 2;
  int t = blockIdx.x * 256 + threadIdx.x;
  if (t < n1) {
    int4 d = ((const int4*)e1d)[t];
    int4 s = ((const int4*)e1s)[t];
    int p;
    p = atomicAdd(&cur1[d.x], 1); csr1[rs1[d.x] + p] = s.x;
    p = atomicAdd(&cur1[d.y], 1); csr1[rs1[d.y] + p] = s.y;
    p = atomicAdd(&cur1[d.z], 1); csr1[rs1[d.z] + p] = s.z;
    p = atomicAdd(&cur1[d.w], 1); csr1[rs1[d.w] + p] = s.w;
  } else if (t < n1 + n2) {
    int4 d = ((const int4*)e2d)[t - n1];
    int4 s = ((const int4*)e2s)[t - n1];
    int p;
    p = atomicAdd(&cur2[d.x], 1); csr2[rs2[d.x] + p] = s.x;
    p = atomicAdd(&cur2[d.y], 1); csr2[rs2[d.y] + p] = s.y;
    p = atomicAdd(&cur2[d.z], 1); csr2[rs2[d.z] + p] = s.z;
    p = atomicAdd(&cur2[d.w], 1); csr2[rs2[d.w] + p] = s.w;
  }
  if (blockIdx.x == 0) {
    int tt = threadIdx.x;
    if (tt < (E1 & 3)) {
      int e = E1 - 1 - tt, d = e1d[e];
      int p = atomicAdd(&cur1[d], 1); csr1[rs1[d] + p] = e1s[e];
    }
    int t2 = tt - 8;
    if (t2 >= 0 && t2 < (E2 & 3)) {
      int e = E2 - 1 - t2, d = e2d[e];
      int p = atomicAdd(&cur2[d], 1); csr2[rs2[d] + p] = e2s[e];
    }
  }
}

// ---------------- weight prep: Wt[col][k0..255] bf16, k<128 = Wself, k>=128 = Wneigh
__global__ void prep_w(const float* __restrict__ Ws1, const float* __restrict__ Wn1,
                       unsigned short* __restrict__ Wt1,
                       const float* __restrict__ Ws2, const float* __restrict__ Wn2,
                       unsigned short* __restrict__ Wt2) {
  int t = blockIdx.x * 256 + threadIdx.x;     // 0..65535
  int which = t >> 15;
  int r = t & 32767;
  int col = r >> 8, k = r & 255;
  const float* Ws = which ? Ws2 : Ws1;
  const float* Wn = which ? Wn2 : Wn1;
  unsigned short* Wt = which ? Wt2 : Wt1;
  float v = (k < 128) ? Ws[k * 128 + col] : Wn[(k - 128) * 128 + col];
  Wt[col * 256 + k] = f2bf(v);
}

// ---------------- gather-mean (f32 src -> bf16 mean), wave per row -----------
// Whole-row 16-edge clamped burst: single latency window per 16 edges; clamped
// lanes re-read the last edge's row (L1 hit, no extra HBM), masked via fmaf.
__global__ __launch_bounds__(256)
void gather_mean1(const float* __restrict__ src, const int* __restrict__ csr,
                  const int* __restrict__ rs, unsigned short* __restrict__ out, int nrows) {
  const int lane = threadIdx.x & 63;
  const int half = lane >> 5;
  const int sub  = lane & 31;
  int row = (int)((blockIdx.x * (unsigned)blockDim.x + threadIdx.x) >> 6);
  row = __builtin_amdgcn_readfirstlane(row);
  if (row >= nrows) return;
  const int start = rs[row], end = rs[row + 1];
  float ax = 0.f, ay = 0.f, az = 0.f, aw = 0.f;
  for (int i = start; i < end; i += 16) {
    const int endm1 = end - 1;
    int cc[16];
    #pragma unroll
    for (int j = 0; j < 16; ++j) { int t = i + j; cc[j] = csr[t < endm1 ? t : endm1]; }
    float4 v[8];
    #pragma unroll
    for (int j = 0; j < 8; ++j) {
      int e = half ? cc[2 * j + 1] : cc[2 * j];
      v[j] = *(const float4*)(src + (size_t)e * FDIM + sub * 4);
    }
    #pragma unroll
    for (int j = 0; j < 8; ++j) {
      float mk = (i + 2 * j + half) < end ? 1.f : 0.f;
      ax = fmaf(v[j].x, mk, ax); ay = fmaf(v[j].y, mk, ay);
      az = fmaf(v[j].z, mk, az); aw = fmaf(v[j].w, mk, aw);
    }
  }
  ax += __shfl_xor(ax, 32); ay += __shfl_xor(ay, 32);
  az += __shfl_xor(az, 32); aw += __shfl_xor(aw, 32);
  if (half == 0) {
    const int deg = end - start;
    const float inv = 1.f / (float)(deg > 1 ? deg : 1);
    ushort4 o;
    o.x = f2bf(ax * inv); o.y = f2bf(ay * inv);
    o.z = f2bf(az * inv); o.w = f2bf(aw * inv);
    *(ushort4*)(out + (size_t)row * FDIM + sub * 4) = o;
  }
}

// gather-mean over bf16 rows (h) -> bf16 mean
__global__ __launch_bounds__(256)
void gather_mean2(const unsigned short* __restrict__ src, const int* __restrict__ csr,
                  const int* __restrict__ rs, unsigned short* __restrict__ out, int nrows) {
  const int lane = threadIdx.x & 63;
  const int half = lane >> 5;
  const int sub  = lane & 31;
  int row = (int)((blockIdx.x * (unsigned)blockDim.x + threadIdx.x) >> 6);
  row = __builtin_amdgcn_readfirstlane(row);
  if (row >= nrows) return;
  const int start = rs[row], end = rs[row + 1];
  float ax = 0.f, ay = 0.f, az = 0.f, aw = 0.f;
  for (int i = start; i < end; i += 16) {
    const int endm1 = end - 1;
    int cc[16];
    #pragma unroll
    for (int j = 0; j < 16; ++j) { int t = i + j; cc[j] = csr[t < endm1 ? t : endm1]; }
    ushort4 v[8];
    #pragma unroll
    for (int j = 0; j < 8; ++j) {
      int e = half ? cc[2 * j + 1] : cc[2 * j];
      v[j] = *(const ushort4*)(src + (size_t)e * FDIM + sub * 4);
    }
    #pragma unroll
    for (int j = 0; j < 8; ++j) {
      float mk = (i + 2 * j + half) < end ? 1.f : 0.f;
      ax = fmaf(bf2f(v[j].x), mk, ax); ay = fmaf(bf2f(v[j].y), mk, ay);
      az = fmaf(bf2f(v[j].z), mk, az); aw = fmaf(bf2f(v[j].w), mk, aw);
    }
  }
  ax += __shfl_xor(ax, 32); ay += __shfl_xor(ay, 32);
  az += __shfl_xor(az, 32); aw += __shfl_xor(aw, 32);
  if (half == 0) {
    const int deg = end - start;
    const float inv = 1.f / (float)(deg > 1 ? deg : 1);
    ushort4 o;
    o.x = f2bf(ax * inv); o.y = f2bf(ay * inv);
    o.z = f2bf(az * inv); o.w = f2bf(aw * inv);
    *(ushort4*)(out + (size_t)row * FDIM + sub * 4) = o;
  }
}

// ---------------- MFMA GEMM: Out = act([Ax|Am] @ [Wself;Wneigh] + b) ---------
// 128-row tile, K=256 (8 chunks of 32), N=128. 4 waves, wave w owns rows w*32..+31.
// mfma_f32_16x16x32_bf16; A-frag: row=lane&15, k=(lane>>4)*8+j; B-frag: col=lane&15,
// k=(lane>>4)*8+j; D: col=lane&15, row=(lane>>4)*4+reg [m89].
template<bool RELU, bool AX_BF16, bool OUT_F32>
__global__ __launch_bounds__(256)
void gemm_mfma(const void* __restrict__ Axp,
               const unsigned short* __restrict__ Am,
               const unsigned short* __restrict__ Wt,
               const float* __restrict__ bias,
               void* __restrict__ Outp) {
  __shared__ unsigned short Asb[128 * LDP];
  __shared__ unsigned short Wsb[128 * LDP];
  const int tid  = threadIdx.x;
  const int lane = tid & 63;
  const int w    = tid >> 6;
  const int row0 = blockIdx.x * 128;
  const int p    = lane & 15;
  const int q    = lane >> 4;

  f32x4 acc[2][8];
  #pragma unroll
  for (int m = 0; m < 2; ++m)
    #pragma unroll
    for (int n = 0; n < 8; ++n) acc[m][n] = (f32x4){0.f, 0.f, 0.f, 0.f};

  const int sr = tid >> 1;            // staging row/col 0..127
  const int sk = (tid & 1) * 16;      // staging k-half

  for (int c = 0; c < 8; ++c) {
    const int kc = c * 32;
    const int kl = kc & 127;
    // stage W chunk (bf16, already [col][k])
    {
      const unsigned short* wsrc = Wt + (size_t)sr * 256 + kc + sk;
      u16x8 a = *(const u16x8*)(wsrc);
      u16x8 b = *(const u16x8*)(wsrc + 8);
      *(u16x8*)&Wsb[sr * LDP + sk]     = a;
      *(u16x8*)&Wsb[sr * LDP + sk + 8] = b;
    }
    // stage A chunk
    if (AX_BF16 || c >= 4) {
      const unsigned short* asrc =
          (c < 4 ? (const unsigned short*)Axp : Am) + (size_t)(row0 + sr) * FDIM + kl + sk;
      u16x8 a = *(const u16x8*)(asrc);
      u16x8 b = *(const u16x8*)(asrc + 8);
      *(u16x8*)&Asb[sr * LDP + sk]     = a;
      *(u16x8*)&Asb[sr * LDP + sk + 8] = b;
    } else {
      const float* asrc = (const float*)Axp + (size_t)(row0 + sr) * FDIM + kl + sk;
      float4 f0 = *(const float4*)(asrc);
      float4 f1 = *(const float4*)(asrc + 4);
      float4 f2 = *(const float4*)(asrc + 8);
      float4 f3 = *(const float4*)(asrc + 12);
      u16x8 a, b;
      a[0] = f2bf(f0.x); a[1] = f2bf(f0.y); a[2] = f2bf(f0.z); a[3] = f2bf(f0.w);
      a[4] = f2bf(f1.x); a[5] = f2bf(f1.y); a[6] = f2bf(f1.z); a[7] = f2bf(f1.w);
      b[0] = f2bf(f2.x); b[1] = f2bf(f2.y); b[2] = f2bf(f2.z); b[3] = f2bf(f2.w);
      b[4] = f2bf(f3.x); b[5] = f2bf(f3.y); b[6] = f2bf(f3.z); b[7] = f2bf(f3.w);
      *(u16x8*)&Asb[sr * LDP + sk]     = a;
      *(u16x8*)&Asb[sr * LDP + sk + 8] = b;
    }
    __syncthreads();
    bf16x8 af[2];
    #pragma unroll
    for (int m = 0; m < 2; ++m)
      af[m] = *(const bf16x8*)&Asb[(w * 32 + m * 16 + p) * LDP + q * 8];
    #pragma unroll
    for (int n = 0; n < 8; ++n) {
      bf16x8 bfr = *(const bf16x8*)&Wsb[(n * 16 + p) * LDP + q * 8];
      acc[0][n] = __builtin_amdgcn_mfma_f32_16x16x32_bf16(af[0], bfr, acc[0][n], 0, 0, 0);
      acc[1][n] = __builtin_amdgcn_mfma_f32_16x16x32_bf16(af[1], bfr, acc[1][n], 0, 0, 0);
    }
    __syncthreads();
  }

  #pragma unroll
  for (int n = 0; n < 8; ++n) {
    const int col = n * 16 + p;
    const float bv = bias[col];
    #pragma unroll
    for (int m = 0; m < 2; ++m) {
      #pragma unroll
      for (int r = 0; r < 4; ++r) {
        float y = acc[m][n][r] + bv;
        if (RELU) y = fmaxf(y, 0.f);
        const size_t grow = (size_t)(row0 + w * 32 + m * 16 + q * 4 + r);
        if (OUT_F32) ((float*)Outp)[grow * FDIM + col] = y;
        else         ((unsigned short*)Outp)[grow * FDIM + col] = f2bf(y);
      }
    }
  }
}

extern "C" void kernel_launch(void* const* d_in, const int* in_sizes, int n_in,
                              void* d_out, int out_size, void* d_ws, size_t ws_size,
                              hipStream_t stream) {
  const float* x   = (const float*)d_in[0];
  const int*   e1s = (const int*)d_in[1];
  const int*   e1d = (const int*)d_in[2];
  const int*   e2s = (const int*)d_in[3];
  const int*   e2d = (const int*)d_in[4];
  const float* Ws1 = (const float*)d_in[7];
  const float* Wn1 = (const float*)d_in[8];
  const float* b1  = (const float*)d_in[9];
  const float* Ws2 = (const float*)d_in[10];
  const float* Wn2 = (const float*)d_in[11];
  const float* b2  = (const float*)d_in[12];
  const int E1 = in_sizes[1];
  const int E2 = in_sizes[3];

  char* pw = (char*)d_ws;
  unsigned short* agg1 = (unsigned short*)pw; pw += (size_t)ND1 * FDIM * 2;  // 32 MB
  unsigned short* h    = (unsigned short*)pw; pw += (size_t)ND1 * FDIM * 2;  // 32 MB
  unsigned short* agg2 = (unsigned short*)pw; pw += (size_t)ND2 * FDIM * 2;  //  2 MB
  unsigned short* Wt1  = (unsigned short*)pw; pw += (size_t)FDIM * 256 * 2;  // 64 KB
  unsigned short* Wt2  = (unsigned short*)pw; pw += (size_t)FDIM * 256 * 2;
  int* csr1 = (int*)pw; pw += (size_t)E1 * 4;
  int* csr2 = (int*)pw; pw += (size_t)E2 * 4;
  int* rs1  = (int*)pw; pw += (size_t)(ND1 + 4) * 4;   // padded to keep 16B alignment
  int* rs2  = (int*)pw; pw += (size_t)(ND2 + 4) * 4;
  int* cur1 = (int*)pw; pw += (size_t)ND1 * 4;
  int* cur2 = (int*)pw; pw += (size_t)ND2 * 4;
  const size_t ZB = (size_t)(ND1 + 4 + ND2 + 4 + ND1 + ND2) * 4;

  hipMemsetAsync(rs1, 0, ZB, stream);
  prep_w<<<256, 256, 0, stream>>>(Ws1, Wn1, Wt1, Ws2, Wn2, Wt2);

  const int n4 = (E1 >> 2) + (E2 >> 2);
  hist_all<<<(n4 + 255) / 256, 256, 0, stream>>>(e1d, e2d, rs1, rs2, E1, E2);
  scan2_kernel<<<2, 1024, 0, stream>>>(rs1, ND1, rs2, ND2);
  fill_all<<<(n4 + 255) / 256, 256, 0, stream>>>(e1s, e1d, e2s, e2d, rs1, rs2,
                                                 cur1, cur2, csr1, csr2, E1, E2);

  // Layer 1: gather-mean(x) -> agg1(bf16); h = relu(x@Ws1 + agg1@Wn1 + b1) (bf16)
  gather_mean1<<<ND1 / 4, 256, 0, stream>>>(x, csr1, rs1, agg1, ND1);
  gemm_mfma<true, false, false><<<ND1 / 128, 256, 0, stream>>>(x, agg1, Wt1, b1, h);

  // Layer 2: gather-mean(h) -> agg2(bf16); out = h@Ws2 + agg2@Wn2 + b2 (f32)
  gather_mean2<<<ND2 / 4, 256, 0, stream>>>(h, csr2, rs2, agg2, ND2);
  gemm_mfma<false, true, true><<<ND2 / 128, 256, 0, stream>>>(h, agg2, Wt2, b2, (float*)d_out);
}

// Round 5
// 479.079 us; speedup vs baseline: 4.7044x; 1.0428x over previous
//
#include <hip/hip_runtime.h>

static constexpr int FDIM = 128;
static constexpr int ND1  = 131072;
static constexpr int ND2  = 8192;
static constexpr int LDP  = 56;   // ushort stride for LDS tiles: 112B rows, 16B-aligned, ~2-way banks

using bf16x8 = __attribute__((ext_vector_type(8))) short;
using u16x8  = __attribute__((ext_vector_type(8))) unsigned short;
using f32x4  = __attribute__((ext_vector_type(4))) float;

static __device__ __forceinline__ unsigned short f2bf(float f) {
  unsigned u = __float_as_uint(f);
  u = (u + 0x7FFFu + ((u >> 16) & 1u)) >> 16;   // round-to-nearest-even
  return (unsigned short)u;
}
static __device__ __forceinline__ float bf2f(unsigned short s) {
  return __uint_as_float(((unsigned)s) << 16);
}

// ---------------- hist (both graphs) + weight prep, one kernel ---------------
__global__ void build_hist(const int* __restrict__ e1d, const int* __restrict__ e2d,
                           int* __restrict__ rs1, int* __restrict__ rs2, int E1, int E2,
                           const float* __restrict__ Ws1, const float* __restrict__ Wn1,
                           unsigned short* __restrict__ Wt1,
                           const float* __restrict__ Ws2, const float* __restrict__ Wn2,
                           unsigned short* __restrict__ Wt2, int nb_hist) {
  if ((int)blockIdx.x >= nb_hist) {   // ---- weight prep: 256 blocks ----
    int t = (blockIdx.x - nb_hist) * 256 + threadIdx.x;   // 0..65535
    int which = t >> 15;
    int r = t & 32767;
    int col = r >> 8, k = r & 255;
    const float* Ws = which ? Ws2 : Ws1;
    const float* Wn = which ? Wn2 : Wn1;
    unsigned short* Wt = which ? Wt2 : Wt1;
    float v = (k < 128) ? Ws[k * 128 + col] : Wn[(k - 128) * 128 + col];
    Wt[col * 256 + k] = f2bf(v);
    return;
  }
  const int n1 = E1 >> 2, n2 = E2 >> 2;
  int t = blockIdx.x * 256 + threadIdx.x;
  if (t < n1) {
    int4 d = ((const int4*)e1d)[t];
    atomicAdd(&rs1[d.x], 1); atomicAdd(&rs1[d.y], 1);
    atomicAdd(&rs1[d.z], 1); atomicAdd(&rs1[d.w], 1);
  } else if (t < n1 + n2) {
    int4 d = ((const int4*)e2d)[t - n1];
    atomicAdd(&rs2[d.x], 1); atomicAdd(&rs2[d.y], 1);
    atomicAdd(&rs2[d.z], 1); atomicAdd(&rs2[d.w], 1);
  }
  if (blockIdx.x == 0) {               // generic tails
    int tt = threadIdx.x;
    if (tt < (E1 & 3)) atomicAdd(&rs1[e1d[E1 - 1 - tt]], 1);
    int t2 = tt - 8;
    if (t2 >= 0 && t2 < (E2 & 3)) atomicAdd(&rs2[e2d[E2 - 1 - t2]], 1);
  }
}

// block 0 scans c1[0..n1), block 1 scans c2[0..n2); total -> c[n]
__global__ __launch_bounds__(1024) void scan2_kernel(int* __restrict__ c1, int n1,
                                                     int* __restrict__ c2, int n2) {
  int* c = blockIdx.x ? c2 : c1;
  const int n = blockIdx.x ? n2 : n1;
  const int tid = threadIdx.x;
  const int chunk = n >> 10;
  const int base = tid * chunk;
  int s = 0;
  for (int j = 0; j < chunk; j += 4) {
    int4 v = *(const int4*)&c[base + j];
    s += v.x + v.y + v.z + v.w;
  }
  __shared__ int ps[1024];
  ps[tid] = s;
  __syncthreads();
  for (int off = 1; off < 1024; off <<= 1) {
    int v = (tid >= off) ? ps[tid - off] : 0;
    __syncthreads();
    ps[tid] += v;
    __syncthreads();
  }
  int run = (tid == 0) ? 0 : ps[tid - 1];
  for (int j = 0; j < chunk; j += 4) {
    int4 v = *(const int4*)&c[base + j];
    int4 o;
    o.x = run; run += v.x; o.y = run; run += v.y;
    o.z = run; run += v.z; o.w = run; run += v.w;
    *(int4*)&c[base + j] = o;
  }
  if (tid == 1023) c[n] = run;
}

__global__ void fill_all(const int* __restrict__ e1s, const int* __restrict__ e1d,
                         const int* __restrict__ e2s, const int* __restrict__ e2d,
                         const int* __restrict__ rs1, const int* __restrict__ rs2,
                         int* __restrict__ cur1, int* __restrict__ cur2,
                         int* __restrict__ csr1, int* __restrict__ csr2, int E1, int E2) {
  const int n1 = E1 >> 2, n2 = E2 >> 2;
  int t = blockIdx.x * 256 + threadIdx.x;
  if (t < n1) {
    int4 d = ((const int4*)e1d)[t];
    int4 s = ((const int4*)e1s)[t];
    int p;
    p = atomicAdd(&cur1[d.x], 1); csr1[rs1[d.x] + p] = s.x;
    p = atomicAdd(&cur1[d.y], 1); csr1[rs1[d.y] + p] = s.y;
    p = atomicAdd(&cur1[d.z], 1); csr1[rs1[d.z] + p] = s.z;
    p = atomicAdd(&cur1[d.w], 1); csr1[rs1[d.w] + p] = s.w;
  } else if (t < n1 + n2) {
    int4 d = ((const int4*)e2d)[t - n1];
    int4 s = ((const int4*)e2s)[t - n1];
    int p;
    p = atomicAdd(&cur2[d.x], 1); csr2[rs2[d.x] + p] = s.x;
    p = atomicAdd(&cur2[d.y], 1); csr2[rs2[d.y] + p] = s.y;
    p = atomicAdd(&cur2[d.z], 1); csr2[rs2[d.z] + p] = s.z;
    p = atomicAdd(&cur2[d.w], 1); csr2[rs2[d.w] + p] = s.w;
  }
  if (blockIdx.x == 0) {
    int tt = threadIdx.x;
    if (tt < (E1 & 3)) {
      int e = E1 - 1 - tt, d = e1d[e];
      int p = atomicAdd(&cur1[d], 1); csr1[rs1[d] + p] = e1s[e];
    }
    int t2 = tt - 8;
    if (t2 >= 0 && t2 < (E2 & 3)) {
      int e = E2 - 1 - t2, d = e2d[e];
      int p = atomicAdd(&cur2[d], 1); csr2[rs2[d] + p] = e2s[e];
    }
  }
}

// ---------------- gather-mean v3: half-wave (32 lanes) per dst row -----------
// One coalesced csr load covers <=32 edges; __shfl broadcasts edge indices;
// 8 row-loads in flight (each VMEM instr serves 2 rows, one per half).
__global__ __launch_bounds__(256)
void gather_mean1(const float* __restrict__ src, const int* __restrict__ csr,
                  const int* __restrict__ rs, unsigned short* __restrict__ out, int nrows) {
  const int tid  = threadIdx.x;
  const int lane = tid & 63;
  const int half = lane >> 5;
  const int sub  = lane & 31;
  const int wid  = (int)((blockIdx.x * 256u + tid) >> 6);
  const int row  = wid * 2 + half;
  if (row >= nrows) return;
  const int start = rs[row];
  const int deg   = rs[row + 1] - start;
  float ax = 0.f, ay = 0.f, az = 0.f, aw = 0.f;
  for (int base = 0; base < deg; base += 32) {
    int t = base + sub;
    int idx = csr[start + (t < deg ? t : deg - 1)];   // coalesced, clamped
    const int lim = (deg - base) < 32 ? (deg - base) : 32;
    for (int b = 0; b < lim; b += 8) {
      float4 v[8];
      #pragma unroll
      for (int j = 0; j < 8; ++j) {
        int e = __shfl(idx, half * 32 + b + j);
        v[j] = *(const float4*)(src + (size_t)e * FDIM + sub * 4);
      }
      #pragma unroll
      for (int j = 0; j < 8; ++j) {
        float mk = (b + j) < lim ? 1.f : 0.f;
        ax = fmaf(v[j].x, mk, ax); ay = fmaf(v[j].y, mk, ay);
        az = fmaf(v[j].z, mk, az); aw = fmaf(v[j].w, mk, aw);
      }
    }
  }
  const float inv = 1.f / (float)(deg > 1 ? deg : 1);
  ushort4 o;
  o.x = f2bf(ax * inv); o.y = f2bf(ay * inv);
  o.z = f2bf(az * inv); o.w = f2bf(aw * inv);
  *(ushort4*)(out + (size_t)row * FDIM + sub * 4) = o;
}

// same, bf16 source rows (h)
__global__ __launch_bounds__(256)
void gather_mean2(const unsigned short* __restrict__ src, const int* __restrict__ csr,
                  const int* __restrict__ rs, unsigned short* __restrict__ out, int nrows) {
  const int tid  = threadIdx.x;
  const int lane = tid & 63;
  const int half = lane >> 5;
  const int sub  = lane & 31;
  const int wid  = (int)((blockIdx.x * 256u + tid) >> 6);
  const int row  = wid * 2 + half;
  if (row >= nrows) return;
  const int start = rs[row];
  const int deg   = rs[row + 1] - start;
  float ax = 0.f, ay = 0.f, az = 0.f, aw = 0.f;
  for (int base = 0; base < deg; base += 32) {
    int t = base + sub;
    int idx = csr[start + (t < deg ? t : deg - 1)];
    const int lim = (deg - base) < 32 ? (deg - base) : 32;
    for (int b = 0; b < lim; b += 8) {
      ushort4 v[8];
      #pragma unroll
      for (int j = 0; j < 8; ++j) {
        int e = __shfl(idx, half * 32 + b + j);
        v[j] = *(const ushort4*)(src + (size_t)e * FDIM + sub * 4);
      }
      #pragma unroll
      for (int j = 0; j < 8; ++j) {
        float mk = (b + j) < lim ? 1.f : 0.f;
        ax = fmaf(bf2f(v[j].x), mk, ax); ay = fmaf(bf2f(v[j].y), mk, ay);
        az = fmaf(bf2f(v[j].z), mk, az); aw = fmaf(bf2f(v[j].w), mk, aw);
      }
    }
  }
  const float inv = 1.f / (float)(deg > 1 ? deg : 1);
  ushort4 o;
  o.x = f2bf(ax * inv); o.y = f2bf(ay * inv);
  o.z = f2bf(az * inv); o.w = f2bf(aw * inv);
  *(ushort4*)(out + (size_t)row * FDIM + sub * 4) = o;
}

// ---------------- MFMA GEMM: Out = act([Ax|Am] @ [Wself;Wneigh] + b) ---------
// 128-row tile, K=256 (8 chunks of 32), N=128. 4 waves, wave w owns rows w*32..+31.
template<bool RELU, bool AX_BF16, bool OUT_F32>
__global__ __launch_bounds__(256)
void gemm_mfma(const void* __restrict__ Axp,
               const unsigned short* __restrict__ Am,
               const unsigned short* __restrict__ Wt,
               const float* __restrict__ bias,
               void* __restrict__ Outp) {
  __shared__ unsigned short Asb[128 * LDP];
  __shared__ unsigned short Wsb[128 * LDP];
  const int tid  = threadIdx.x;
  const int lane = tid & 63;
  const int w    = tid >> 6;
  const int row0 = blockIdx.x * 128;
  const int p    = lane & 15;
  const int q    = lane >> 4;

  f32x4 acc[2][8];
  #pragma unroll
  for (int m = 0; m < 2; ++m)
    #pragma unroll
    for (int n = 0; n < 8; ++n) acc[m][n] = (f32x4){0.f, 0.f, 0.f, 0.f};

  const int sr = tid >> 1;            // staging row/col 0..127
  const int sk = (tid & 1) * 16;      // staging k-half

  for (int c = 0; c < 8; ++c) {
    const int kc = c * 32;
    const int kl = kc & 127;
    {
      const unsigned short* wsrc = Wt + (size_t)sr * 256 + kc + sk;
      u16x8 a = *(const u16x8*)(wsrc);
      u16x8 b = *(const u16x8*)(wsrc + 8);
      *(u16x8*)&Wsb[sr * LDP + sk]     = a;
      *(u16x8*)&Wsb[sr * LDP + sk + 8] = b;
    }
    if (AX_BF16 || c >= 4) {
      const unsigned short* asrc =
          (c < 4 ? (const unsigned short*)Axp : Am) + (size_t)(row0 + sr) * FDIM + kl + sk;
      u16x8 a = *(const u16x8*)(asrc);
      u16x8 b = *(const u16x8*)(asrc + 8);
      *(u16x8*)&Asb[sr * LDP + sk]     = a;
      *(u16x8*)&Asb[sr * LDP + sk + 8] = b;
    } else {
      const float* asrc = (const float*)Axp + (size_t)(row0 + sr) * FDIM + kl + sk;
      float4 f0 = *(const float4*)(asrc);
      float4 f1 = *(const float4*)(asrc + 4);
      float4 f2 = *(const float4*)(asrc + 8);
      float4 f3 = *(const float4*)(asrc + 12);
      u16x8 a, b;
      a[0] = f2bf(f0.x); a[1] = f2bf(f0.y); a[2] = f2bf(f0.z); a[3] = f2bf(f0.w);
      a[4] = f2bf(f1.x); a[5] = f2bf(f1.y); a[6] = f2bf(f1.z); a[7] = f2bf(f1.w);
      b[0] = f2bf(f2.x); b[1] = f2bf(f2.y); b[2] = f2bf(f2.z); b[3] = f2bf(f2.w);
      b[4] = f2bf(f3.x); b[5] = f2bf(f3.y); b[6] = f2bf(f3.z); b[7] = f2bf(f3.w);
      *(u16x8*)&Asb[sr * LDP + sk]     = a;
      *(u16x8*)&Asb[sr * LDP + sk + 8] = b;
    }
    __syncthreads();
    bf16x8 af[2];
    #pragma unroll
    for (int m = 0; m < 2; ++m)
      af[m] = *(const bf16x8*)&Asb[(w * 32 + m * 16 + p) * LDP + q * 8];
    #pragma unroll
    for (int n = 0; n < 8; ++n) {
      bf16x8 bfr = *(const bf16x8*)&Wsb[(n * 16 + p) * LDP + q * 8];
      acc[0][n] = __builtin_amdgcn_mfma_f32_16x16x32_bf16(af[0], bfr, acc[0][n], 0, 0, 0);
      acc[1][n] = __builtin_amdgcn_mfma_f32_16x16x32_bf16(af[1], bfr, acc[1][n], 0, 0, 0);
    }
    __syncthreads();
  }

  #pragma unroll
  for (int n = 0; n < 8; ++n) {
    const int col = n * 16 + p;
    const float bv = bias[col];
    #pragma unroll
    for (int m = 0; m < 2; ++m) {
      #pragma unroll
      for (int r = 0; r < 4; ++r) {
        float y = acc[m][n][r] + bv;
        if (RELU) y = fmaxf(y, 0.f);
        const size_t grow = (size_t)(row0 + w * 32 + m * 16 + q * 4 + r);
        if (OUT_F32) ((float*)Outp)[grow * FDIM + col] = y;
        else         ((unsigned short*)Outp)[grow * FDIM + col] = f2bf(y);
      }
    }
  }
}

extern "C" void kernel_launch(void* const* d_in, const int* in_sizes, int n_in,
                              void* d_out, int out_size, void* d_ws, size_t ws_size,
                              hipStream_t stream) {
  const float* x   = (const float*)d_in[0];
  const int*   e1s = (const int*)d_in[1];
  const int*   e1d = (const int*)d_in[2];
  const int*   e2s = (const int*)d_in[3];
  const int*   e2d = (const int*)d_in[4];
  const float* Ws1 = (const float*)d_in[7];
  const float* Wn1 = (const float*)d_in[8];
  const float* b1  = (const float*)d_in[9];
  const float* Ws2 = (const float*)d_in[10];
  const float* Wn2 = (const float*)d_in[11];
  const float* b2  = (const float*)d_in[12];
  const int E1 = in_sizes[1];
  const int E2 = in_sizes[3];

  char* pw = (char*)d_ws;
  unsigned short* agg1 = (unsigned short*)pw; pw += (size_t)ND1 * FDIM * 2;  // 32 MB
  unsigned short* h    = (unsigned short*)pw; pw += (size_t)ND1 * FDIM * 2;  // 32 MB
  unsigned short* agg2 = (unsigned short*)pw; pw += (size_t)ND2 * FDIM * 2;  //  2 MB
  unsigned short* Wt1  = (unsigned short*)pw; pw += (size_t)FDIM * 256 * 2;  // 64 KB
  unsigned short* Wt2  = (unsigned short*)pw; pw += (size_t)FDIM * 256 * 2;
  int* csr1 = (int*)pw; pw += (size_t)E1 * 4;
  int* csr2 = (int*)pw; pw += (size_t)E2 * 4;
  int* rs1  = (int*)pw; pw += (size_t)(ND1 + 4) * 4;   // padded, keeps 16B alignment
  int* rs2  = (int*)pw; pw += (size_t)(ND2 + 4) * 4;
  int* cur1 = (int*)pw; pw += (size_t)ND1 * 4;
  int* cur2 = (int*)pw; pw += (size_t)ND2 * 4;
  const size_t ZB = (size_t)(ND1 + 4 + ND2 + 4 + ND1 + ND2) * 4;

  hipMemsetAsync(rs1, 0, ZB, stream);

  const int n4 = (E1 >> 2) + (E2 >> 2);
  const int nb_hist = (n4 + 255) / 256;
  build_hist<<<nb_hist + 256, 256, 0, stream>>>(e1d, e2d, rs1, rs2, E1, E2,
                                                Ws1, Wn1, Wt1, Ws2, Wn2, Wt2, nb_hist);
  scan2_kernel<<<2, 1024, 0, stream>>>(rs1, ND1, rs2, ND2);
  fill_all<<<(n4 + 255) / 256, 256, 0, stream>>>(e1s, e1d, e2s, e2d, rs1, rs2,
                                                 cur1, cur2, csr1, csr2, E1, E2);

  // Layer 1: gather-mean(x) -> agg1(bf16); h = relu(x@Ws1 + agg1@Wn1 + b1) (bf16)
  gather_mean1<<<ND1 / 8, 256, 0, stream>>>(x, csr1, rs1, agg1, ND1);
  gemm_mfma<true, false, false><<<ND1 / 128, 256, 0, stream>>>(x, agg1, Wt1, b1, h);

  // Layer 2: gather-mean(h) -> agg2(bf16); out = h@Ws2 + agg2@Wn2 + b2 (f32)
  gather_mean2<<<ND2 / 8, 256, 0, stream>>>(h, csr2, rs2, agg2, ND2);
  gemm_mfma<false, true, true><<<ND2 / 128, 256, 0, stream>>>(h, agg2, Wt2, b2, (float*)d_out);
}